// Round 4
// baseline (87.912 us; speedup 1.0000x reference)
//
#include <hip/hip_runtime.h>

typedef __bf16 bf16x8 __attribute__((ext_vector_type(8)));
typedef __bf16 bf16x2 __attribute__((ext_vector_type(2)));
typedef float  f32x4  __attribute__((ext_vector_type(4)));

// ws layout (bytes). All A-operand fragments lane-linear:
// one frag = 1024 B; lane l's 16 B at frag_base + l*16.
//   WT0 : 8 frags   (nt 0..7)            bytes [0      .. 8191  ]
//   WTH : 160 frags ((h*4+ks)*8 + nt)    bytes [8192   .. 172031]
//   WLT : 4 frags   (ks 0..3)            bytes [172032 .. 176127]
#define WS_WT0_B 0
#define WS_WTH_B 8192
#define WS_WLT_B 172032

__device__ __forceinline__ unsigned short f2b(float f) {
  return __builtin_bit_cast(unsigned short, (__bf16)f);
}

__global__ void prep_kernel(const float* __restrict__ W0,
                            const float* __restrict__ Wh,
                            const float* __restrict__ WL,
                            unsigned short* __restrict__ ws) {
  int i = blockIdx.x * 256 + threadIdx.x;   // ushort index == (byte/2)
  int l  = (i >> 3) & 63;                   // lane within frag
  int j  = i & 7;                           // element within lane's 8
  int lm = l & 15, lh = l >> 4;
  if (i < 4096) {                           // WT0, frag nt = i>>9 ; K=32 zero-padded
    int nt = i >> 9;
    int n = nt * 16 + lm, k = lh * 8 + j;
    ws[i] = f2b(k < 4 ? W0[k * 128 + n] : 0.f);
  } else if (i < 86016) {                   // WTH
    int t = i - 4096;
    int frag = t >> 9;                      // (h*4+ks)*8 + nt
    int nt = frag & 7, ks = (frag >> 3) & 3, h = frag >> 5;
    int n = nt * 16 + lm, k = ks * 32 + lh * 8 + j;
    ws[i] = f2b(Wh[(h * 128 + k) * 128 + n]);
  } else if (i < 88064) {                   // WLT, frag ks ; n>=2 zero-padded
    int t = i - 86016;
    int ks = t >> 9;
    int n = lm, k = ks * 32 + lh * 8 + j;
    ws[i] = f2b(n < 2 ? WL[k * 2 + n] : 0.f);
  }
}

__device__ __forceinline__ f32x4 swish4(f32x4 z) {
  f32x4 e;
  e[0] = __expf(-z[0]); e[1] = __expf(-z[1]);
  e[2] = __expf(-z[2]); e[3] = __expf(-z[3]);
  const f32x4 w = e + 1.f;
  f32x4 s;
  s[0] = __builtin_amdgcn_rcpf(w[0]); s[1] = __builtin_amdgcn_rcpf(w[1]);
  s[2] = __builtin_amdgcn_rcpf(w[2]); s[3] = __builtin_amdgcn_rcpf(w[3]);
  return z * s;
}

// pack f32x4 -> 2x u32 of bf16 pairs (v_cvt_pk_bf16_f32 path)
__device__ __forceinline__ uint2 pack4(f32x4 r) {
  bf16x2 lo = {(__bf16)r[0], (__bf16)r[1]};
  bf16x2 hi = {(__bf16)r[2], (__bf16)r[3]};
  uint2 wv;
  wv.x = __builtin_bit_cast(unsigned int, lo);
  wv.y = __builtin_bit_cast(unsigned int, hi);
  return wv;
}

// 4 independent waves per block; each wave owns 32 points, no barriers.
__launch_bounds__(256, 4)
__global__ void mlp_kernel(const float* __restrict__ X,
                           const float* __restrict__ nu_min_p,
                           const float* __restrict__ nu_max_p,
                           const float* __restrict__ b0,
                           const float* __restrict__ bh,
                           const float* __restrict__ bL,
                           const unsigned short* __restrict__ ws,
                           float* __restrict__ out) {
  __shared__ __align__(16) char HsAll[4][32 * 256];  // 8 KB per wave
  const int lane = threadIdx.x & 63;
  const int wave = threadIdx.x >> 6;
  char* Hs = HsAll[wave];
  const int lm = lane & 15, lh = lane >> 4;
  const int row0 = blockIdx.x * 128 + wave * 32;
  const char* wsb = reinterpret_cast<const char*>(ws);
  const char* ap  = wsb + lane * 16;            // per-lane A-frag pointer
  const int xorm = (lm & 7) << 4;

  // precomputed LDS addresses (verified: rd(pt,ks)=va[pt]^(ks<<6), wr(nt,pt)=wa[pt]^(nt<<5))
  const int va0 = lm * 256 + ((lh * 16) ^ xorm);
  const int va1 = va0 + 16 * 256;
  const int wa0 = lm * 256 + ((lh * 8) ^ xorm);
  const int wa1 = wa0 + 16 * 256;

  // ---- stage scaled inputs (K padded to 32 -> 64B rows) ----
  if (lane < 32) {
    const float4 xv = reinterpret_cast<const float4*>(X)[row0 + lane];
    const float numin = nu_min_p[0], numax = nu_max_p[0];
    const float v0 = xv.x;
    const float v1 = xv.y;
    const float v2 = 2.f * xv.z - 1.f;
    const float v3 = 2.f * (xv.w - numin) / (numax - numin) - 1.f;
    uint4 c0;
    c0.x = (unsigned)f2b(v0) | ((unsigned)f2b(v1) << 16);
    c0.y = (unsigned)f2b(v2) | ((unsigned)f2b(v3) << 16);
    c0.z = 0u; c0.w = 0u;
    const uint4 z4 = make_uint4(0u, 0u, 0u, 0u);
    const int xr = (lane & 7) << 4;
    char* rp = Hs + lane * 256;
    *reinterpret_cast<uint4*>(rp + (0  ^ xr)) = c0;
    *reinterpret_cast<uint4*>(rp + (16 ^ xr)) = z4;
    *reinterpret_cast<uint4*>(rp + (32 ^ xr)) = z4;
    *reinterpret_cast<uint4*>(rp + (48 ^ xr)) = z4;
  }

  f32x4 acc[8][2];

  // ================= Layer 0 : K = 32 (single ks) =================
  {
    bf16x8 bfr[2];
    bfr[0] = __builtin_bit_cast(bf16x8, *reinterpret_cast<const uint4*>(Hs + va0));
    bfr[1] = __builtin_bit_cast(bf16x8, *reinterpret_cast<const uint4*>(Hs + va1));
#pragma unroll
    for (int nt = 0; nt < 8; ++nt) {
      const f32x4 bv = *reinterpret_cast<const f32x4*>(b0 + nt * 16 + lh * 4);
      const bf16x8 a = __builtin_bit_cast(bf16x8,
          *reinterpret_cast<const uint4*>(ap + WS_WT0_B + nt * 1024));
      acc[nt][0] = __builtin_amdgcn_mfma_f32_16x16x32_bf16(a, bfr[0], bv, 0, 0, 0);
      acc[nt][1] = __builtin_amdgcn_mfma_f32_16x16x32_bf16(a, bfr[1], bv, 0, 0, 0);
    }
#pragma unroll
    for (int nt = 0; nt < 8; ++nt) {
#pragma unroll
      for (int pt = 0; pt < 2; ++pt) {
        const uint2 wv = pack4(swish4(acc[nt][pt]));
        const int wa = (pt ? wa1 : wa0) ^ (nt << 5);
        *reinterpret_cast<uint2*>(Hs + wa) = wv;
      }
    }
  }

  // ================= 5 hidden layers : K = 128, in-place, fully unrolled =================
#pragma unroll
  for (int h = 0; h < 5; ++h) {
    const float* bias = bh + h * 128;
#pragma unroll
    for (int ks = 0; ks < 4; ++ks) {
      bf16x8 bfr[2];
      bfr[0] = __builtin_bit_cast(bf16x8,
          *reinterpret_cast<const uint4*>(Hs + (va0 ^ (ks << 6))));
      bfr[1] = __builtin_bit_cast(bf16x8,
          *reinterpret_cast<const uint4*>(Hs + (va1 ^ (ks << 6))));
#pragma unroll
      for (int nt = 0; nt < 8; ++nt) {
        const bf16x8 a = __builtin_bit_cast(bf16x8,
            *reinterpret_cast<const uint4*>(ap + WS_WTH_B + h * 32768 + (ks * 8 + nt) * 1024));
        if (ks == 0) {
          const f32x4 bv = *reinterpret_cast<const f32x4*>(bias + nt * 16 + lh * 4);
          acc[nt][0] = __builtin_amdgcn_mfma_f32_16x16x32_bf16(a, bfr[0], bv, 0, 0, 0);
          acc[nt][1] = __builtin_amdgcn_mfma_f32_16x16x32_bf16(a, bfr[1], bv, 0, 0, 0);
        } else {
          acc[nt][0] = __builtin_amdgcn_mfma_f32_16x16x32_bf16(a, bfr[0], acc[nt][0], 0, 0, 0);
          acc[nt][1] = __builtin_amdgcn_mfma_f32_16x16x32_bf16(a, bfr[1], acc[nt][1], 0, 0, 0);
        }
      }
    }
#pragma unroll
    for (int nt = 0; nt < 8; ++nt) {
#pragma unroll
      for (int pt = 0; pt < 2; ++pt) {
        const uint2 wv = pack4(swish4(acc[nt][pt]));
        const int wa = (pt ? wa1 : wa0) ^ (nt << 5);
        *reinterpret_cast<uint2*>(Hs + wa) = wv;
      }
    }
  }

  // ================= final layer : [128 -> 2] via MFMA =================
  {
    const float bl0 = bL[0], bl1 = bL[1];
#pragma unroll
    for (int pt = 0; pt < 2; ++pt) {
      f32x4 accL = {0.f, 0.f, 0.f, 0.f};
#pragma unroll
      for (int ks = 0; ks < 4; ++ks) {
        const bf16x8 bfr = __builtin_bit_cast(bf16x8,
            *reinterpret_cast<const uint4*>(Hs + ((pt ? va1 : va0) ^ (ks << 6))));
        const bf16x8 a = __builtin_bit_cast(bf16x8,
            *reinterpret_cast<const uint4*>(ap + WS_WLT_B + ks * 1024));
        accL = __builtin_amdgcn_mfma_f32_16x16x32_bf16(a, bfr, accL, 0, 0, 0);
      }
      if (lh == 0) {
        const int p = pt * 16 + lm;
        float2 o;
        o.x = accL[0] + bl0;
        o.y = accL[1] + bl1;
        *reinterpret_cast<float2*>(out + (size_t)(row0 + p) * 2) = o;
      }
    }
  }
}

extern "C" void kernel_launch(void* const* d_in, const int* in_sizes, int n_in,
                              void* d_out, int out_size, void* d_ws, size_t ws_size,
                              hipStream_t stream) {
  const float* X     = (const float*)d_in[0];
  const float* numin = (const float*)d_in[1];
  const float* numax = (const float*)d_in[2];
  const float* W0    = (const float*)d_in[3];
  const float* b0    = (const float*)d_in[4];
  const float* Wh    = (const float*)d_in[5];
  const float* bh    = (const float*)d_in[6];
  const float* WL    = (const float*)d_in[7];
  const float* bL    = (const float*)d_in[8];
  unsigned short* ws = (unsigned short*)d_ws;
  float* out = (float*)d_out;

  hipLaunchKernelGGL(prep_kernel, dim3(344), dim3(256), 0, stream, W0, Wh, WL, ws);
  hipLaunchKernelGGL(mlp_kernel, dim3(2048), dim3(256), 0, stream,
                     X, numin, numax, b0, bh, bL, ws, out);
}